// Round 3
// baseline (78.094 us; speedup 1.0000x reference)
//
#include <hip/hip_runtime.h>
#include <stdint.h>

#define NSTRUCT 8
#define NROWS   1024
#define DD      128

// Fused kernel: per block (o, col-quarter of 32 cols, row-tile of 128 rows)
//  Phase A: Threefry2x32-20 (JAX partitionable: bits = out0^out1) -> M slice in LDS
//  Phase B: stage x row-tile transposed (XOR-swizzled) into LDS
//  Phase C: register-tiled GEMM  out[o,n,c] = sum_p x[n,p] * M[o,p,c]
//
// Grid: 8 * 4 * 8 = 256 blocks, 256 threads. LDS 80 KB -> 1 block/CU.
// Inner loop: 1 ds_read_b128 (M) + 1 ds_read_b128 (x, swizzled) + 16 v_fmac.

__device__ __forceinline__ uint32_t rotl32(uint32_t x, uint32_t d) {
  return (x << d) | (x >> (32u - d));
}

__device__ __forceinline__ uint32_t threefry_bits(uint32_t i) {
  const uint32_t ks0 = 0u;
  const uint32_t ks1 = 42u;
  const uint32_t ks2 = 0x1BD11BDAu ^ ks0 ^ ks1;
  uint32_t x0 = 0u + ks0;   // counts_hi = 0
  uint32_t x1 = i  + ks1;   // counts_lo = flat (o,p,c) index
#define TF_RND(r) { x0 += x1; x1 = rotl32(x1, r); x1 ^= x0; }
  TF_RND(13) TF_RND(15) TF_RND(26) TF_RND(6)
  x0 += ks1; x1 += ks2 + 1u;
  TF_RND(17) TF_RND(29) TF_RND(16) TF_RND(24)
  x0 += ks2; x1 += ks0 + 2u;
  TF_RND(13) TF_RND(15) TF_RND(26) TF_RND(6)
  x0 += ks0; x1 += ks1 + 3u;
  TF_RND(17) TF_RND(29) TF_RND(16) TF_RND(24)
  x0 += ks1; x1 += ks2 + 4u;
  TF_RND(13) TF_RND(15) TF_RND(26) TF_RND(6)
  x0 += ks2; x1 += ks0 + 5u;
#undef TF_RND
  return x0 ^ x1;  // partitionable 32-bit draw
}

__global__ __launch_bounds__(256, 1) void nnl0_fused(
    const float* __restrict__ x,
    const float* __restrict__ maskings,
    const float* __restrict__ theta,
    const float* __restrict__ W,
    float* __restrict__ out) {
  __shared__ float Ms[DD * 32];   // [p][c] 16 KB, c contiguous
  __shared__ float xs[DD * DD];   // [p][g^ (p&31)][4] transposed+swizzled, 64 KB

  const int b   = blockIdx.x;
  const int o   = b >> 5;              // structure 0..7
  const int cq  = (b >> 3) & 3;       // col quarter 0..3
  const int rt  = b & 7;              // row tile 0..7
  const int n0  = rt << 7;            // 128-row tile base
  const int cb  = cq << 5;            // 32-col slice base
  const int tid = threadIdx.x;

  // ---- Phase A: build M slice [p=0..127][c=0..31] in LDS ----
  {
    const int mbase = o * DD * DD;   // flat (o,*,*) base
#pragma unroll 2
    for (int k = 0; k < 16; ++k) {
      int idx = k * 256 + tid;       // 0..4095 within slice
      int p = idx >> 5;
      int c = idx & 31;
      int gi = mbase + p * DD + cb + c;    // global flat (o,p,c)
      uint32_t bits = threefry_bits((uint32_t)gi);
      float u = __uint_as_float((bits >> 9) | 0x3f800000u) - 1.0f;
      float v = (u < theta[gi]) ? maskings[gi] * W[gi] : 0.0f;
      Ms[p * 32 + c] = v;   // banks: c%32 distinct -> conflict-free
    }
  }

  // ---- Phase B: stage x rows n0..n0+127 transposed into xs (XOR swizzle) ----
  // write:  x[n0+n][p]  ->  xs[p*128 + ((n>>2) ^ (p&31))*4 + (n&3)]
#pragma unroll 2
  for (int k = 0; k < 16; ++k) {
    int q = k * 256 + tid;           // 0..4095 float4 chunks
    int n = q >> 5;                  // local row 0..127
    int pc = (q & 31) << 2;          // p base 0,4,...,124
    float4 v = *(const float4*)&x[(size_t)(n0 + n) * DD + pc];
    int g = n >> 2, nj = n & 3;
    xs[(pc + 0) * DD + ((g ^ ((pc + 0) & 31)) << 2) + nj] = v.x;
    xs[(pc + 1) * DD + ((g ^ ((pc + 1) & 31)) << 2) + nj] = v.y;
    xs[(pc + 2) * DD + ((g ^ ((pc + 2) & 31)) << 2) + nj] = v.z;
    xs[(pc + 3) * DD + ((g ^ ((pc + 3) & 31)) << 2) + nj] = v.w;
  }

  __syncthreads();

  // ---- Phase C: GEMM. micro-tile 4 rows x 4 cols per thread ----
  const int c0 = (tid & 7) << 2;     // 0,4,...,28 within 32-col slice
  const int g  = tid >> 3;           // row group 0..31 (rows g*4..g*4+3)

  float acc[4][4];
#pragma unroll
  for (int a = 0; a < 4; ++a)
#pragma unroll
    for (int bb = 0; bb < 4; ++bb) acc[a][bb] = 0.0f;

#pragma unroll 4
  for (int p = 0; p < DD; ++p) {
    float4 bv = *(const float4*)&Ms[p * 32 + c0];
    float4 av = *(const float4*)&xs[p * DD + ((g ^ (p & 31)) << 2)];
    acc[0][0] += av.x * bv.x; acc[0][1] += av.x * bv.y; acc[0][2] += av.x * bv.z; acc[0][3] += av.x * bv.w;
    acc[1][0] += av.y * bv.x; acc[1][1] += av.y * bv.y; acc[1][2] += av.y * bv.z; acc[1][3] += av.y * bv.w;
    acc[2][0] += av.z * bv.x; acc[2][1] += av.z * bv.y; acc[2][2] += av.z * bv.z; acc[2][3] += av.z * bv.w;
    acc[3][0] += av.w * bv.x; acc[3][1] += av.w * bv.y; acc[3][2] += av.w * bv.z; acc[3][3] += av.w * bv.w;
  }

  // ---- Epilogue: rows n0+g*4+j, cols cb+c0..+3 ----
  float* obase = out + ((size_t)o * NROWS + n0 + g * 4) * DD + cb + c0;
#pragma unroll
  for (int j = 0; j < 4; ++j) {
    *(float4*)&obase[(size_t)j * DD] =
        make_float4(acc[j][0], acc[j][1], acc[j][2], acc[j][3]);
  }
}

extern "C" void kernel_launch(void* const* d_in, const int* in_sizes, int n_in,
                              void* d_out, int out_size, void* d_ws, size_t ws_size,
                              hipStream_t stream) {
  const float* x        = (const float*)d_in[0];
  const float* maskings = (const float*)d_in[1];
  const float* theta    = (const float*)d_in[2];
  const float* W        = (const float*)d_in[3];
  float* out = (float*)d_out;

  nnl0_fused<<<NSTRUCT * 4 * 8, 256, 0, stream>>>(x, maskings, theta, W, out);
}

// Round 4
// 68.449 us; speedup vs baseline: 1.1409x; 1.1409x over previous
//
#include <hip/hip_runtime.h>
#include <stdint.h>

#define NSTRUCT 8
#define NROWS   1024
#define DD      128

// ---------------------------------------------------------------------------
// Kernel A: M[o,p,c] = maskings * (u < theta) * W
// JAX threefry2x32, partitionable path: bits = out0 ^ out1 (verified R2,
// absmax 0.0). u = bitcast((bits>>9)|0x3f800000) - 1.0
// ---------------------------------------------------------------------------

__device__ __forceinline__ uint32_t rotl32(uint32_t x, uint32_t d) {
  return (x << d) | (x >> (32u - d));
}

__global__ __launch_bounds__(256) void build_M(
    const float* __restrict__ maskings,
    const float* __restrict__ theta,
    const float* __restrict__ W,
    float* __restrict__ M) {
  uint32_t i = blockIdx.x * 256u + threadIdx.x;  // 0 .. 131071 (flat o,p,c)

  const uint32_t ks0 = 0u;
  const uint32_t ks1 = 42u;
  const uint32_t ks2 = 0x1BD11BDAu ^ ks0 ^ ks1;

  uint32_t x0 = 0u + ks0;   // counts_hi = 0
  uint32_t x1 = i  + ks1;   // counts_lo = flat index

#define TF_RND(r) { x0 += x1; x1 = rotl32(x1, r); x1 ^= x0; }
  TF_RND(13) TF_RND(15) TF_RND(26) TF_RND(6)
  x0 += ks1; x1 += ks2 + 1u;
  TF_RND(17) TF_RND(29) TF_RND(16) TF_RND(24)
  x0 += ks2; x1 += ks0 + 2u;
  TF_RND(13) TF_RND(15) TF_RND(26) TF_RND(6)
  x0 += ks0; x1 += ks1 + 3u;
  TF_RND(17) TF_RND(29) TF_RND(16) TF_RND(24)
  x0 += ks1; x1 += ks2 + 4u;
  TF_RND(13) TF_RND(15) TF_RND(26) TF_RND(6)
  x0 += ks2; x1 += ks0 + 5u;
#undef TF_RND

  uint32_t bits = x0 ^ x1;  // partitionable 32-bit draw
  float u = __uint_as_float((bits >> 9) | 0x3f800000u) - 1.0f;
  M[i] = (u < theta[i]) ? maskings[i] * W[i] : 0.0f;
}

// ---------------------------------------------------------------------------
// Kernel B: x_hat[o,n,c] = sum_p x[n,p] * M[o,p,c]
// Grid: 8 structures x 64 row-tiles (16 rows) = 512 blocks, 256 threads.
// LDS: FULL M[o] (128x128, 64 KB) + x tile (16x128, 8 KB) = 72 KB
//   -> 2 blocks/CU (144 KB < 160 KB), 8 waves/CU, ONE barrier total.
// Micro-tile: 2 rows x 4 cols/thread; inner loop does 4 p per step:
//   4x ds_read_b128 M (conflict-free) + 2x ds_read_b128 x (broadcast) + 32 FMA.
// ---------------------------------------------------------------------------

__global__ __launch_bounds__(256, 2) void sem_gemm(
    const float* __restrict__ x,
    const float* __restrict__ M,
    float* __restrict__ out) {
  __shared__ float Ms[DD * DD];   // 64 KB, [p][c]
  __shared__ float xs[16 * DD];   // 8 KB,  [n][p]

  const int o   = blockIdx.x >> 6;         // structure 0..7
  const int n0  = (blockIdx.x & 63) << 4;  // 16-row tile base
  const int tid = threadIdx.x;

  // stage full M[o]: 4096 float4, 16 per thread, coalesced
  {
    const float4* src = (const float4*)(M + (size_t)o * DD * DD);
    float4* dst = (float4*)Ms;
#pragma unroll
    for (int k = 0; k < 16; ++k) dst[tid + k * 256] = src[tid + k * 256];
  }
  // stage x tile: 512 float4, 2 per thread, coalesced
  {
    const float4* src = (const float4*)(x + (size_t)n0 * DD);
    float4* dst = (float4*)xs;
#pragma unroll
    for (int k = 0; k < 2; ++k) dst[tid + k * 256] = src[tid + k * 256];
  }
  __syncthreads();

  const int c0 = (tid & 31) << 2;   // col 0,4,...,124
  const int r0 = (tid >> 5) << 1;   // row pair 0,2,...,14

  float acc0[4] = {0.f, 0.f, 0.f, 0.f};
  float acc1[4] = {0.f, 0.f, 0.f, 0.f};

#pragma unroll 4
  for (int p0 = 0; p0 < DD; p0 += 4) {
    float4 a0 = *(const float4*)&xs[(r0 + 0) * DD + p0];  // broadcast
    float4 a1 = *(const float4*)&xs[(r0 + 1) * DD + p0];  // broadcast
    float4 b0 = *(const float4*)&Ms[(p0 + 0) * DD + c0];
    float4 b1 = *(const float4*)&Ms[(p0 + 1) * DD + c0];
    float4 b2 = *(const float4*)&Ms[(p0 + 2) * DD + c0];
    float4 b3 = *(const float4*)&Ms[(p0 + 3) * DD + c0];

    acc0[0] += a0.x * b0.x; acc0[1] += a0.x * b0.y; acc0[2] += a0.x * b0.z; acc0[3] += a0.x * b0.w;
    acc0[0] += a0.y * b1.x; acc0[1] += a0.y * b1.y; acc0[2] += a0.y * b1.z; acc0[3] += a0.y * b1.w;
    acc0[0] += a0.z * b2.x; acc0[1] += a0.z * b2.y; acc0[2] += a0.z * b2.z; acc0[3] += a0.z * b2.w;
    acc0[0] += a0.w * b3.x; acc0[1] += a0.w * b3.y; acc0[2] += a0.w * b3.z; acc0[3] += a0.w * b3.w;

    acc1[0] += a1.x * b0.x; acc1[1] += a1.x * b0.y; acc1[2] += a1.x * b0.z; acc1[3] += a1.x * b0.w;
    acc1[0] += a1.y * b1.x; acc1[1] += a1.y * b1.y; acc1[2] += a1.y * b1.z; acc1[3] += a1.y * b1.w;
    acc1[0] += a1.z * b2.x; acc1[1] += a1.z * b2.y; acc1[2] += a1.z * b2.z; acc1[3] += a1.z * b2.w;
    acc1[0] += a1.w * b3.x; acc1[1] += a1.w * b3.y; acc1[2] += a1.w * b3.z; acc1[3] += a1.w * b3.w;
  }

  float* obase = out + ((size_t)o * NROWS + n0 + r0) * DD + c0;
  *(float4*)&obase[0]  = make_float4(acc0[0], acc0[1], acc0[2], acc0[3]);
  *(float4*)&obase[DD] = make_float4(acc1[0], acc1[1], acc1[2], acc1[3]);
}

// ---------------------------------------------------------------------------

extern "C" void kernel_launch(void* const* d_in, const int* in_sizes, int n_in,
                              void* d_out, int out_size, void* d_ws, size_t ws_size,
                              hipStream_t stream) {
  const float* x        = (const float*)d_in[0];
  const float* maskings = (const float*)d_in[1];
  const float* theta    = (const float*)d_in[2];
  const float* W        = (const float*)d_in[3];
  float* out = (float*)d_out;
  float* M   = (float*)d_ws;  // 8*128*128 fp32 = 512 KB scratch

  build_M<<<(NSTRUCT * DD * DD) / 256, 256, 0, stream>>>(maskings, theta, W, M);
  sem_gemm<<<NSTRUCT * (NROWS / 16), 256, 0, stream>>>(x, M, out);
}

// Round 5
// 62.576 us; speedup vs baseline: 1.2480x; 1.0938x over previous
//
#include <hip/hip_runtime.h>
#include <stdint.h>

#define NSTRUCT 8
#define NROWS   1024
#define DD      128

typedef short bf16x8 __attribute__((ext_vector_type(8)));  // 8 bf16 (4 VGPRs)
typedef float f32x4  __attribute__((ext_vector_type(4)));  // 4 fp32 acc

// ---------------------------------------------------------------------------
// Threefry2x32-20, JAX partitionable path: bits = out0 ^ out1 (verified R2,
// absmax 0.0 vs jax reference). u = bitcast((bits>>9)|0x3f800000) - 1.0
// ---------------------------------------------------------------------------
__device__ __forceinline__ uint32_t rotl32(uint32_t x, uint32_t d) {
  return (x << d) | (x >> (32u - d));
}

__device__ __forceinline__ uint32_t threefry_bits(uint32_t i) {
  const uint32_t ks0 = 0u;
  const uint32_t ks1 = 42u;
  const uint32_t ks2 = 0x1BD11BDAu ^ ks0 ^ ks1;
  uint32_t x0 = 0u + ks0;   // counts_hi = 0
  uint32_t x1 = i  + ks1;   // counts_lo = flat (o,p,c) index
#define TF_RND(r) { x0 += x1; x1 = rotl32(x1, r); x1 ^= x0; }
  TF_RND(13) TF_RND(15) TF_RND(26) TF_RND(6)
  x0 += ks1; x1 += ks2 + 1u;
  TF_RND(17) TF_RND(29) TF_RND(16) TF_RND(24)
  x0 += ks2; x1 += ks0 + 2u;
  TF_RND(13) TF_RND(15) TF_RND(26) TF_RND(6)
  x0 += ks0; x1 += ks1 + 3u;
  TF_RND(17) TF_RND(29) TF_RND(16) TF_RND(24)
  x0 += ks1; x1 += ks2 + 4u;
  TF_RND(13) TF_RND(15) TF_RND(26) TF_RND(6)
  x0 += ks2; x1 += ks0 + 5u;
#undef TF_RND
  return x0 ^ x1;
}

__device__ __forceinline__ uint16_t f32_to_bf16_rne(float v) {
  uint32_t fb = __float_as_uint(v);
  uint32_t lsb = (fb >> 16) & 1u;
  return (uint16_t)((fb + 0x7fffu + lsb) >> 16);
}

// ---------------------------------------------------------------------------
// build_frags: write M (masked Bernoulli * W) and x in MFMA fragment order.
// MFMA 16x16x32 bf16 layouts (m89/m120-verified):
//   A-operand: lane holds A[m=lane&15][k=(lane>>4)*8+j], j=0..7
//   B-operand: lane holds B[k=(lane>>4)*8+j][n=lane&15]
//   C/D:       lane,reg -> row=(lane>>4)*4+reg, col=lane&15
// Mb layout: [o(8)][ct(8)][kk(4)][lane(64)][j(8)]  (B-frag major) 256 KB
// xb layout: [rt(64)][kk(4)][lane(64)][j(8)]       (A-frag major) 256 KB
// Writes are 2 B/thread, consecutive -> coalesced. Reads are small gathers
// (L2/L3-resident inputs).
// ---------------------------------------------------------------------------
__global__ __launch_bounds__(256) void build_frags(
    const float* __restrict__ x,
    const float* __restrict__ maskings,
    const float* __restrict__ theta,
    const float* __restrict__ W,
    uint16_t* __restrict__ Mb,
    uint16_t* __restrict__ xb) {
  const int b = blockIdx.x;
  const int tid = threadIdx.x;
  if (b < 512) {
    // M fragment: flat = ((((o*8+ct)*4+kk)*64+lane)*8+j)
    uint32_t flat = (uint32_t)b * 256u + tid;
    uint32_t j    = flat & 7u;
    uint32_t lane = (flat >> 3) & 63u;
    uint32_t kk   = (flat >> 9) & 3u;
    uint32_t ct   = (flat >> 11) & 7u;
    uint32_t o    = flat >> 14;
    uint32_t p = kk * 32u + (lane >> 4) * 8u + j;   // K index
    uint32_t c = ct * 16u + (lane & 15u);           // N index
    uint32_t gi = (o << 14) | (p << 7) | c;         // flat (o,p,c)
    uint32_t bits = threefry_bits(gi);
    float u = __uint_as_float((bits >> 9) | 0x3f800000u) - 1.0f;
    float v = (u < theta[gi]) ? maskings[gi] * W[gi] : 0.0f;
    Mb[flat] = f32_to_bf16_rne(v);
  } else {
    // x fragment: idx = ((rt*4+kk)*64+lane)*8+j
    uint32_t idx  = (uint32_t)(b - 512) * 256u + tid;
    uint32_t j    = idx & 7u;
    uint32_t lane = (idx >> 3) & 63u;
    uint32_t kk   = (idx >> 9) & 3u;
    uint32_t rt   = idx >> 11;                      // 16-row tile 0..63
    uint32_t n = rt * 16u + (lane & 15u);           // M index (row)
    uint32_t k = kk * 32u + (lane >> 4) * 8u + j;   // K index
    xb[idx] = f32_to_bf16_rne(x[n * DD + k]);
  }
}

// ---------------------------------------------------------------------------
// sem_mfma: out[o,n,c] = sum_p x[n,p] * M[o,p,c] via bf16 MFMA, fp32 accum.
// Grid: 8 structs x 32 row-blocks (32 rows) = 256 blocks x 256 thr (4 waves).
// Wave w: row-tile rb*2+(w&1), col-tiles 4*(w>>1)..+3. No LDS, no barrier:
// fragments loaded straight from global (L2-resident). 16 MFMA/wave.
// ---------------------------------------------------------------------------
__global__ __launch_bounds__(256) void sem_mfma(
    const uint16_t* __restrict__ Mb,
    const uint16_t* __restrict__ xb,
    float* __restrict__ out) {
  const int bidx = blockIdx.x;
  const int o    = bidx >> 5;        // structure 0..7
  const int rb   = bidx & 31;        // 32-row block
  const int tid  = threadIdx.x;
  const int w    = tid >> 6;         // wave 0..3
  const int lane = tid & 63;
  const int rt_g = rb * 2 + (w & 1); // global 16-row tile 0..63
  const int ctb  = (w >> 1) * 4;     // col-tile base 0 or 4

  const bf16x8* xbv = (const bf16x8*)xb;
  const bf16x8* mbv = (const bf16x8*)Mb;

  bf16x8 a[4];
#pragma unroll
  for (int kk = 0; kk < 4; ++kk) a[kk] = xbv[(rt_g * 4 + kk) * 64 + lane];

  f32x4 acc[4] = {{0.f, 0.f, 0.f, 0.f}, {0.f, 0.f, 0.f, 0.f},
                  {0.f, 0.f, 0.f, 0.f}, {0.f, 0.f, 0.f, 0.f}};

#pragma unroll
  for (int t = 0; t < 4; ++t) {
    const int ct = ctb + t;
#pragma unroll
    for (int kk = 0; kk < 4; ++kk) {
      bf16x8 bfrag = mbv[((o * 8 + ct) * 4 + kk) * 64 + lane];
      acc[t] = __builtin_amdgcn_mfma_f32_16x16x32_bf16(a[kk], bfrag, acc[t], 0, 0, 0);
    }
  }

  // C/D layout: row = (lane>>4)*4 + reg, col = lane&15
  const int col0     = lane & 15;
  const int row_base = rb * 32 + (w & 1) * 16 + (lane >> 4) * 4;
#pragma unroll
  for (int t = 0; t < 4; ++t) {
    const int col = (ctb + t) * 16 + col0;
#pragma unroll
    for (int r = 0; r < 4; ++r) {
      out[((size_t)o * NROWS + row_base + r) * DD + col] = acc[t][r];
    }
  }
}

// ---------------------------------------------------------------------------

extern "C" void kernel_launch(void* const* d_in, const int* in_sizes, int n_in,
                              void* d_out, int out_size, void* d_ws, size_t ws_size,
                              hipStream_t stream) {
  const float* x        = (const float*)d_in[0];
  const float* maskings = (const float*)d_in[1];
  const float* theta    = (const float*)d_in[2];
  const float* W        = (const float*)d_in[3];
  float* out = (float*)d_out;

  uint16_t* Mb = (uint16_t*)d_ws;                       // 256 KB (B-frag order)
  uint16_t* xb = Mb + NSTRUCT * DD * DD;                // 256 KB (A-frag order)

  build_frags<<<1024, 256, 0, stream>>>(x, maskings, theta, W, Mb, xb);
  sem_mfma<<<NSTRUCT * 32, 256, 0, stream>>>(Mb, xb, out);
}